// Round 9
// baseline (277.600 us; speedup 1.0000x reference)
//
#include <hip/hip_runtime.h>

#define TPB 256
#define ROWS_PER_B 128     // fallback streaming kernel
#define ITEMS_PER_BLK 128  // gather kernel: items per block (2 threads/item)

// y is exactly 0.0f or 1.0f; -(y*log(p) + (1-y)*log1p(-p)) reduces to a select.
__device__ __forceinline__ float bce1(float p, float y) {
    return (y > 0.5f) ? -__logf(p) : -__logf(1.0f - p);
}
__device__ __forceinline__ float bce4(float4 p, float4 y) {
    return bce1(p.x, y.x) + bce1(p.y, y.y) + bce1(p.z, y.z) + bce1(p.w, y.w);
}

template<int N>
__device__ __forceinline__ void block_reduce_store(const double* vals, double* slot) {
    __shared__ double sm[4][N];
    const int lane = threadIdx.x & 63;
    const int wid  = threadIdx.x >> 6;
    #pragma unroll
    for (int j = 0; j < N; ++j) {
        double v = vals[j];
        #pragma unroll
        for (int o = 32; o > 0; o >>= 1)
            v += __shfl_down(v, o, 64);
        if (lane == 0) sm[wid][j] = v;
    }
    __syncthreads();
    if (threadIdx.x == 0) {
        #pragma unroll
        for (int j = 0; j < N; ++j)
            slot[j] = sm[0][j] + sm[1][j] + sm[2][j] + sm[3][j];
    }
}

// ---- kernel A: l1+l2 sums, ballot-compacted per-entry active row lists ----
__global__ void __launch_bounds__(TPB) hml_A(
    const float* __restrict__ l1p, const float* __restrict__ l2pCC,
    const float* __restrict__ l2pURW, const float* __restrict__ l1y,
    const float* __restrict__ l2yCC, const float* __restrict__ l2yURW,
    int nrows, double* __restrict__ pA,
    unsigned* __restrict__ cnt, unsigned* __restrict__ lists)
{
    double s1 = 0, s2cc = 0, s2urw = 0, nCC = 0, nURW = 0;
    const int i = blockIdx.x * TPB + threadIdx.x;   // one row per thread
    bool b[5] = { false, false, false, false, false };

    if (i < nrows) {
        float2 p1 = ((const float2*)l1p)[i];
        float2 y1 = ((const float2*)l1y)[i];
        float2 pu = ((const float2*)l2pURW)[i];
        float2 yu = ((const float2*)l2yURW)[i];
        float c0p = l2pCC[i*3+0], c1p = l2pCC[i*3+1], c2p = l2pCC[i*3+2];
        float c0y = l2yCC[i*3+0], c1y = l2yCC[i*3+1], c2y = l2yCC[i*3+2];

        s1 = (double)(bce1(p1.x, y1.x) + bce1(p1.y, y1.y));

        const bool aCC  = (y1.x > 0.5f);
        const bool aURW = (y1.y > 0.5f);
        const float fCC  = aCC  ? 1.f : 0.f;
        const float fURW = aURW ? 1.f : 0.f;

        s2cc  = (double)(fCC  * (bce1(c0p, c0y) + bce1(c1p, c1y) + bce1(c2p, c2y)));
        s2urw = (double)(fURW * (bce1(pu.x, yu.x) + bce1(pu.y, yu.y)));
        nCC   = (double)fCC;
        nURW  = (double)fURW;

        b[0] = aCC  && (c0y  != 0.f);
        b[1] = aCC  && (c1y  != 0.f);
        b[2] = aCC  && (c2y  != 0.f);
        b[3] = aURW && (yu.x != 0.f);
        b[4] = aURW && (yu.y != 0.f);
    }

    // per-entry wave-ballot compaction: one atomic per wave per entry
    const int lane = threadIdx.x & 63;
    #pragma unroll
    for (int e = 0; e < 5; ++e) {
        const unsigned long long m = __ballot(b[e]);
        unsigned base = 0;
        if (lane == 0 && m != 0ull)
            base = atomicAdd(&cnt[e], (unsigned)__popcll(m));
        base = (unsigned)__shfl((int)base, 0, 64);
        if (b[e]) {
            const unsigned off = (unsigned)__popcll(m & ((1ull << lane) - 1ull));
            lists[(size_t)e * (size_t)nrows + base + off] = (unsigned)i;
        }
    }

    double vals[5] = { s1, s2cc, s2urw, nCC, nURW };
    block_reduce_store<5>(vals, pA + (size_t)blockIdx.x * 8);
}

// ---- kernel B: gather of ACTIVE rows only; entry = blockIdx.y (uniform ptr) ----
// Block (chunk, e) owns items [chunk*128, chunk*128+128) of list[e].
// Thread t: item = chunk*128 + (t>>1), half = t&1 -> 8 unconditional dwordx4
// loads of a dense 64B segment pair (full lines). Static schedule, no fences.
__global__ void __launch_bounds__(TPB) hml_Bg(
    const float* __restrict__ p3a, const float* __restrict__ p3b,
    const float* __restrict__ p3c, const float* __restrict__ p3d,
    const float* __restrict__ p3e,
    const float* __restrict__ y3a, const float* __restrict__ y3b,
    const float* __restrict__ y3c, const float* __restrict__ y3d,
    const float* __restrict__ y3e,
    const unsigned* __restrict__ cnt, const unsigned* __restrict__ lists,
    int nrows, double* __restrict__ pB)
{
    const int      e     = blockIdx.y;
    const unsigned c     = cnt[e];
    const unsigned first = blockIdx.x * ITEMS_PER_BLK;
    const int      slot  = blockIdx.y * gridDim.x + blockIdx.x;

    if (first >= c) {                      // uniform early-exit for empty blocks
        if (threadIdx.x == 0) pB[slot] = 0.0;
        return;
    }

    const float* P[5] = { p3a, p3b, p3c, p3d, p3e };
    const float* Q[5] = { y3a, y3b, y3c, y3d, y3e };
    const float4* __restrict__ p4 = (const float4*)P[e];   // block-uniform (SGPR)
    const float4* __restrict__ q4 = (const float4*)Q[e];

    const unsigned idx   = first + (threadIdx.x >> 1);
    const bool     valid = idx < c;
    const unsigned row   = lists[(size_t)e * (size_t)nrows + (valid ? idx : first)];
    const long     base  = (long)row * 8 + (threadIdx.x & 1) * 4;

    // 8 independent unconditional 16B loads (64B contiguous per thread)
    float4 p0 = p4[base+0], p1 = p4[base+1], p2 = p4[base+2], p3_ = p4[base+3];
    float4 q0 = q4[base+0], q1 = q4[base+1], q2 = q4[base+2], q3_ = q4[base+3];

    const float mf = valid ? 1.f : 0.f;
    double s3 = (double)(mf * (bce4(p0, q0) + bce4(p1, q1)
                             + bce4(p2, q2) + bce4(p3_, q3_)));

    double vals[1] = { s3 };
    block_reduce_store<1>(vals, pB + slot);
}

// ---- fallback kernel B: full static stream with mask byte (r8 replica) ----
__global__ void __launch_bounds__(TPB) hml_Bs(
    const float* __restrict__ p3a, const float* __restrict__ p3b,
    const float* __restrict__ p3c, const float* __restrict__ p3d,
    const float* __restrict__ p3e,
    const float* __restrict__ y3a, const float* __restrict__ y3b,
    const float* __restrict__ y3c, const float* __restrict__ y3d,
    const float* __restrict__ y3e,
    const float* __restrict__ l1y, const float* __restrict__ l2yCC,
    const float* __restrict__ l2yURW,
    int nrows, double* __restrict__ pB)
{
    const int  row  = blockIdx.x * ROWS_PER_B + (threadIdx.x >> 1);
    const int  half = threadIdx.x & 1;
    const long base = (long)row * 8 + half * 4;

    double s3 = 0;

    if (row < nrows) {
        float2 y1 = ((const float2*)l1y)[row];
        float2 yu = ((const float2*)l2yURW)[row];
        float  c0 = l2yCC[row*3+0], c1 = l2yCC[row*3+1], c2 = l2yCC[row*3+2];
        const bool aCC  = (y1.x > 0.5f);
        const bool aURW = (y1.y > 0.5f);
        float mfs[5];
        mfs[0] = (aCC  && c0   != 0.f) ? 1.f : 0.f;
        mfs[1] = (aCC  && c1   != 0.f) ? 1.f : 0.f;
        mfs[2] = (aCC  && c2   != 0.f) ? 1.f : 0.f;
        mfs[3] = (aURW && yu.x != 0.f) ? 1.f : 0.f;
        mfs[4] = (aURW && yu.y != 0.f) ? 1.f : 0.f;

        const float4* P[5] = { (const float4*)p3a, (const float4*)p3b, (const float4*)p3c,
                               (const float4*)p3d, (const float4*)p3e };
        const float4* Q[5] = { (const float4*)y3a, (const float4*)y3b, (const float4*)y3c,
                               (const float4*)y3d, (const float4*)y3e };
        #pragma unroll
        for (int e = 0; e < 5; ++e) {
            const float4* __restrict__ p4 = P[e] + base;
            const float4* __restrict__ q4 = Q[e] + base;
            float4 p0 = p4[0], p1 = p4[1], p2 = p4[2], p3_ = p4[3];
            float4 q0 = q4[0], q1 = q4[1], q2 = q4[2], q3_ = q4[3];
            s3 += (double)(mfs[e] * (bce4(p0, q0) + bce4(p1, q1)
                                   + bce4(p2, q2) + bce4(p3_, q3_)));
        }
    }

    double vals[1] = { s3 };
    block_reduce_store<1>(vals, pB + blockIdx.x);
}

// ---- final: reduce partial slots + counters, apply formula ----
__global__ void __launch_bounds__(TPB) hml_final(
    const double* __restrict__ pA, int nA,
    const double* __restrict__ pB, int nB,
    const unsigned* __restrict__ cnt,   // may be null (fallback: n3 in pA[5])
    float* __restrict__ out, int nrows, int useCnt)
{
    double S[7] = { 0, 0, 0, 0, 0, 0, 0 };  // s1,s2cc,s2urw,nCC,nURW,n3,s3

    for (int i = threadIdx.x; i < nA; i += TPB) {
        #pragma unroll
        for (int j = 0; j < 5; ++j) S[j] += pA[(size_t)i * 8 + j];
        if (!useCnt) S[5] += pA[(size_t)i * 8 + 5];
    }
    for (int i = threadIdx.x; i < nB; i += TPB)
        S[6] += pB[i];

    __shared__ double sm[4][7];
    const int lane = threadIdx.x & 63;
    const int wid  = threadIdx.x >> 6;
    #pragma unroll
    for (int j = 0; j < 7; ++j) {
        double v = S[j];
        #pragma unroll
        for (int o = 32; o > 0; o >>= 1)
            v += __shfl_down(v, o, 64);
        if (lane == 0) sm[wid][j] = v;
    }
    __syncthreads();

    if (threadIdx.x == 0) {
        double s1   = sm[0][0] + sm[1][0] + sm[2][0] + sm[3][0];
        double s2cc = sm[0][1] + sm[1][1] + sm[2][1] + sm[3][1];
        double s2u  = sm[0][2] + sm[1][2] + sm[2][2] + sm[3][2];
        double nCC  = sm[0][3] + sm[1][3] + sm[2][3] + sm[3][3];
        double nU   = sm[0][4] + sm[1][4] + sm[2][4] + sm[3][4];
        double n3   = sm[0][5] + sm[1][5] + sm[2][5] + sm[3][5];
        double s3   = sm[0][6] + sm[1][6] + sm[2][6] + sm[3][6];
        if (useCnt)
            n3 = (double)(cnt[0] + cnt[1] + cnt[2] + cnt[3] + cnt[4]);

        double level1 = s1 / ((double)nrows * 2.0);
        double l2 = 0.0;
        if (nCC > 0.0) l2 += s2cc / (nCC * 3.0);
        if (nU  > 0.0) l2 += s2u  / (nU  * 2.0);
        double level2 = 0.5 * l2;
        double level3 = (n3 > 0.0) ? (s3 / 32.0) / n3 : 0.0;

        out[0] = (float)(level1 + level2 + level3);
    }
}

// fallback kernel A (r8 replica: mask-byte + n3 in slot[5])
__global__ void __launch_bounds__(TPB) hml_A_mask(
    const float* __restrict__ l1p, const float* __restrict__ l2pCC,
    const float* __restrict__ l2pURW, const float* __restrict__ l1y,
    const float* __restrict__ l2yCC, const float* __restrict__ l2yURW,
    int nrows, double* __restrict__ pA)
{
    double s1 = 0, s2cc = 0, s2urw = 0, nCC = 0, nURW = 0, n3 = 0;
    const long i = (long)blockIdx.x * blockDim.x + threadIdx.x;

    if (i < nrows) {
        float2 p1 = ((const float2*)l1p)[i];
        float2 y1 = ((const float2*)l1y)[i];
        float2 pu = ((const float2*)l2pURW)[i];
        float2 yu = ((const float2*)l2yURW)[i];
        float c0p = l2pCC[i*3+0], c1p = l2pCC[i*3+1], c2p = l2pCC[i*3+2];
        float c0y = l2yCC[i*3+0], c1y = l2yCC[i*3+1], c2y = l2yCC[i*3+2];

        s1 = (double)(bce1(p1.x, y1.x) + bce1(p1.y, y1.y));
        const bool aCC  = (y1.x > 0.5f);
        const bool aURW = (y1.y > 0.5f);
        const float fCC  = aCC  ? 1.f : 0.f;
        const float fURW = aURW ? 1.f : 0.f;
        s2cc  = (double)(fCC  * (bce1(c0p, c0y) + bce1(c1p, c1y) + bce1(c2p, c2y)));
        s2urw = (double)(fURW * (bce1(pu.x, yu.x) + bce1(pu.y, yu.y)));
        nCC   = (double)fCC;
        nURW  = (double)fURW;
        n3 = (double)(((aCC  && c0y  != 0.f) ? 1 : 0) +
                      ((aCC  && c1y  != 0.f) ? 1 : 0) +
                      ((aCC  && c2y  != 0.f) ? 1 : 0) +
                      ((aURW && yu.x != 0.f) ? 1 : 0) +
                      ((aURW && yu.y != 0.f) ? 1 : 0));
    }

    double vals[6] = { s1, s2cc, s2urw, nCC, nURW, n3 };
    block_reduce_store<6>(vals, pA + (size_t)blockIdx.x * 8);
}

extern "C" void kernel_launch(void* const* d_in, const int* in_sizes, int n_in,
                              void* d_out, int out_size, void* d_ws, size_t ws_size,
                              hipStream_t stream) {
    const float* l1p   = (const float*)d_in[0];
    const float* l2pCC = (const float*)d_in[1];
    const float* l2pURW= (const float*)d_in[2];
    const float* p3a   = (const float*)d_in[3];
    const float* p3b   = (const float*)d_in[4];
    const float* p3c   = (const float*)d_in[5];
    const float* p3d   = (const float*)d_in[6];
    const float* p3e   = (const float*)d_in[7];
    const float* l1y   = (const float*)d_in[8];
    const float* l2yCC = (const float*)d_in[9];
    const float* l2yURW= (const float*)d_in[10];
    const float* y3a   = (const float*)d_in[11];
    const float* y3b   = (const float*)d_in[12];
    const float* y3c   = (const float*)d_in[13];
    const float* y3d   = (const float*)d_in[14];
    const float* y3e   = (const float*)d_in[15];

    const int nrows = in_sizes[0] / 2;
    const int nA    = (nrows + TPB - 1) / TPB;                       // 1024
    const int nbpe  = (nrows + ITEMS_PER_BLK - 1) / ITEMS_PER_BLK;   // 2048
    const int nBg   = nbpe * 5;                                      // 10240

    // ws layout: pA (nA*8 dbl) | pB (nBg dbl) | cnt (5 u32, padded 32B) | lists (5*nrows u32)
    double*   pA    = (double*)d_ws;
    double*   pB    = (double*)((char*)d_ws + (size_t)nA * 8 * sizeof(double));
    unsigned* cnt   = (unsigned*)((char*)pB + (size_t)nBg * sizeof(double));
    unsigned* lists = (unsigned*)((char*)cnt + 32);

    const size_t need = (size_t)nA * 8 * sizeof(double)
                      + (size_t)nBg * sizeof(double) + 32
                      + (size_t)nrows * 5 * sizeof(unsigned);

    if (ws_size >= need) {
        hipMemsetAsync(cnt, 0, 32, stream);
        hml_A<<<nA, TPB, 0, stream>>>(
            l1p, l2pCC, l2pURW, l1y, l2yCC, l2yURW, nrows, pA, cnt, lists);
        hml_Bg<<<dim3(nbpe, 5), TPB, 0, stream>>>(
            p3a, p3b, p3c, p3d, p3e, y3a, y3b, y3c, y3d, y3e,
            cnt, lists, nrows, pB);
        hml_final<<<1, TPB, 0, stream>>>(pA, nA, pB, nBg, cnt,
                                         (float*)d_out, nrows, 1);
    } else {
        const int nBs = (nrows + ROWS_PER_B - 1) / ROWS_PER_B;       // 2048
        hml_A_mask<<<nA, TPB, 0, stream>>>(
            l1p, l2pCC, l2pURW, l1y, l2yCC, l2yURW, nrows, pA);
        hml_Bs<<<nBs, TPB, 0, stream>>>(
            p3a, p3b, p3c, p3d, p3e, y3a, y3b, y3c, y3d, y3e,
            l1y, l2yCC, l2yURW, nrows, pB);
        hml_final<<<1, TPB, 0, stream>>>(pA, nA, pB, nBs, nullptr,
                                         (float*)d_out, nrows, 0);
    }
}

// Round 10
// 37.512 us; speedup vs baseline: 7.4003x; 7.4003x over previous
//
#include <hip/hip_runtime.h>

#define TPB 256
#define ROWS_PER_B 128   // B-kernel: one block = 128 rows, fully static schedule

// y is exactly 0.0f or 1.0f; -(y*log(p) + (1-y)*log1p(-p)) reduces to a select.
__device__ __forceinline__ float bce1(float p, float y) {
    return (y > 0.5f) ? -__logf(p) : -__logf(1.0f - p);
}
__device__ __forceinline__ float bce4(float4 p, float4 y) {
    return bce1(p.x, y.x) + bce1(p.y, y.y) + bce1(p.z, y.z) + bce1(p.w, y.w);
}

// block-reduce N doubles (shuffle + LDS), thread0 plain-stores to slot[j]
template<int N>
__device__ __forceinline__ void block_reduce_store(const double* vals, double* slot) {
    __shared__ double sm[4][N];
    const int lane = threadIdx.x & 63;
    const int wid  = threadIdx.x >> 6;
    #pragma unroll
    for (int j = 0; j < N; ++j) {
        double v = vals[j];
        #pragma unroll
        for (int o = 32; o > 0; o >>= 1)
            v += __shfl_down(v, o, 64);
        if (lane == 0) sm[wid][j] = v;
    }
    __syncthreads();
    if (threadIdx.x == 0) {
        #pragma unroll
        for (int j = 0; j < N; ++j)
            slot[j] = sm[0][j] + sm[1][j] + sm[2][j] + sm[3][j];
    }
}

// ---- kernel A: level1+level2 sums, per-row 5-bit mask byte, partials to slots ----
// (r8 replica — no contended atomics: one plain store per block)
__global__ void __launch_bounds__(TPB) hml_A(
    const float* __restrict__ l1p, const float* __restrict__ l2pCC,
    const float* __restrict__ l2pURW, const float* __restrict__ l1y,
    const float* __restrict__ l2yCC, const float* __restrict__ l2yURW,
    int nrows, double* __restrict__ pA, unsigned char* __restrict__ mask)
{
    double s1 = 0, s2cc = 0, s2urw = 0, nCC = 0, nURW = 0, n3 = 0;
    const long i = (long)blockIdx.x * blockDim.x + threadIdx.x;   // one row per thread

    if (i < nrows) {
        float2 p1 = ((const float2*)l1p)[i];
        float2 y1 = ((const float2*)l1y)[i];
        float2 pu = ((const float2*)l2pURW)[i];
        float2 yu = ((const float2*)l2yURW)[i];
        float c0p = l2pCC[i*3+0], c1p = l2pCC[i*3+1], c2p = l2pCC[i*3+2];
        float c0y = l2yCC[i*3+0], c1y = l2yCC[i*3+1], c2y = l2yCC[i*3+2];

        s1 = (double)(bce1(p1.x, y1.x) + bce1(p1.y, y1.y));

        const bool aCC  = (y1.x > 0.5f);
        const bool aURW = (y1.y > 0.5f);
        const float fCC  = aCC  ? 1.f : 0.f;
        const float fURW = aURW ? 1.f : 0.f;

        s2cc  = (double)(fCC  * (bce1(c0p, c0y) + bce1(c1p, c1y) + bce1(c2p, c2y)));
        s2urw = (double)(fURW * (bce1(pu.x, yu.x) + bce1(pu.y, yu.y)));
        nCC   = (double)fCC;
        nURW  = (double)fURW;

        const unsigned b0 = (aCC  && c0y  != 0.f) ? 1u : 0u;
        const unsigned b1 = (aCC  && c1y  != 0.f) ? 1u : 0u;
        const unsigned b2 = (aCC  && c2y  != 0.f) ? 1u : 0u;
        const unsigned b3 = (aURW && yu.x != 0.f) ? 1u : 0u;
        const unsigned b4 = (aURW && yu.y != 0.f) ? 1u : 0u;
        n3 = (double)(b0 + b1 + b2 + b3 + b4);
        mask[i] = (unsigned char)(b0 | (b1 << 1) | (b2 << 2) | (b3 << 3) | (b4 << 4));
    }

    double vals[6] = { s1, s2cc, s2urw, nCC, nURW, n3 };
    block_reduce_store<6>(vals, pA + (size_t)blockIdx.x * 8);
}

// ---- kernel B: level3 — r8's static schedule + ADDRESS-SELECT traffic skip ----
// Same shape as r8 (one block = 128 rows, 2 threads/row, 8 unconditional
// dwordx4 per entry, static offsets). Only change: per-lane pointer select —
// inactive (row,entry) lanes load from the array base (one globally hot,
// L1-resident line) instead of their row, so they fetch no unique HBM lines.
// No branches, no divergence, no new dependencies; result bit-identical
// (dummy values are finite and multiplied by mf = 0).
__global__ void __launch_bounds__(TPB) hml_B(
    const float* __restrict__ p3a, const float* __restrict__ p3b,
    const float* __restrict__ p3c, const float* __restrict__ p3d,
    const float* __restrict__ p3e,
    const float* __restrict__ y3a, const float* __restrict__ y3b,
    const float* __restrict__ y3c, const float* __restrict__ y3d,
    const float* __restrict__ y3e,
    const unsigned char* __restrict__ mask,
    int nrows, double* __restrict__ pB)
{
    const int  row  = blockIdx.x * ROWS_PER_B + (threadIdx.x >> 1);
    const long base = (long)row * 8 + (threadIdx.x & 1) * 4;   // float4 index

    const unsigned mb = (row < nrows) ? (unsigned)mask[row] : 0u;

    const float4* P[5] = { (const float4*)p3a, (const float4*)p3b, (const float4*)p3c,
                           (const float4*)p3d, (const float4*)p3e };
    const float4* Q[5] = { (const float4*)y3a, (const float4*)y3b, (const float4*)y3c,
                           (const float4*)y3d, (const float4*)y3e };

    double s3 = 0;

    #pragma unroll
    for (int e = 0; e < 5; ++e) {
        const bool act = ((mb >> e) & 1u) != 0u;
        // pointer select: active -> this row's 64B half; inactive -> array base
        const float4* __restrict__ p4 = act ? (P[e] + base) : P[e];
        const float4* __restrict__ q4 = act ? (Q[e] + base) : Q[e];

        // 8 independent unconditional 16B loads, static offsets
        float4 p0 = p4[0], p1 = p4[1], p2 = p4[2], p3_ = p4[3];
        float4 q0 = q4[0], q1 = q4[1], q2 = q4[2], q3_ = q4[3];

        const float mf = act ? 1.f : 0.f;
        s3 += (double)(mf * (bce4(p0, q0) + bce4(p1, q1)
                           + bce4(p2, q2) + bce4(p3_, q3_)));
    }

    double vals[1] = { s3 };
    block_reduce_store<1>(vals, pB + blockIdx.x);
}

// ---- final: reduce partial slots, apply formula ----
__global__ void __launch_bounds__(TPB) hml_final(
    const double* __restrict__ pA, int nA,
    const double* __restrict__ pB, int nB,
    float* __restrict__ out, int nrows)
{
    double S[7] = { 0, 0, 0, 0, 0, 0, 0 };   // s1,s2cc,s2urw,nCC,nURW,n3,s3

    for (int i = threadIdx.x; i < nA; i += TPB) {
        #pragma unroll
        for (int j = 0; j < 6; ++j) S[j] += pA[(size_t)i * 8 + j];
    }
    for (int i = threadIdx.x; i < nB; i += TPB)
        S[6] += pB[i];

    __shared__ double sm[4][7];
    const int lane = threadIdx.x & 63;
    const int wid  = threadIdx.x >> 6;
    #pragma unroll
    for (int j = 0; j < 7; ++j) {
        double v = S[j];
        #pragma unroll
        for (int o = 32; o > 0; o >>= 1)
            v += __shfl_down(v, o, 64);
        if (lane == 0) sm[wid][j] = v;
    }
    __syncthreads();

    if (threadIdx.x == 0) {
        double s1   = sm[0][0] + sm[1][0] + sm[2][0] + sm[3][0];
        double s2cc = sm[0][1] + sm[1][1] + sm[2][1] + sm[3][1];
        double s2u  = sm[0][2] + sm[1][2] + sm[2][2] + sm[3][2];
        double nCC  = sm[0][3] + sm[1][3] + sm[2][3] + sm[3][3];
        double nU   = sm[0][4] + sm[1][4] + sm[2][4] + sm[3][4];
        double n3   = sm[0][5] + sm[1][5] + sm[2][5] + sm[3][5];
        double s3   = sm[0][6] + sm[1][6] + sm[2][6] + sm[3][6];

        double level1 = s1 / ((double)nrows * 2.0);
        double l2 = 0.0;
        if (nCC > 0.0) l2 += s2cc / (nCC * 3.0);
        if (nU  > 0.0) l2 += s2u  / (nU  * 2.0);
        double level2 = 0.5 * l2;
        double level3 = (n3 > 0.0) ? (s3 / 32.0) / n3 : 0.0;

        out[0] = (float)(level1 + level2 + level3);
    }
}

extern "C" void kernel_launch(void* const* d_in, const int* in_sizes, int n_in,
                              void* d_out, int out_size, void* d_ws, size_t ws_size,
                              hipStream_t stream) {
    const float* l1p   = (const float*)d_in[0];
    const float* l2pCC = (const float*)d_in[1];
    const float* l2pURW= (const float*)d_in[2];
    const float* p3a   = (const float*)d_in[3];
    const float* p3b   = (const float*)d_in[4];
    const float* p3c   = (const float*)d_in[5];
    const float* p3d   = (const float*)d_in[6];
    const float* p3e   = (const float*)d_in[7];
    const float* l1y   = (const float*)d_in[8];
    const float* l2yCC = (const float*)d_in[9];
    const float* l2yURW= (const float*)d_in[10];
    const float* y3a   = (const float*)d_in[11];
    const float* y3b   = (const float*)d_in[12];
    const float* y3c   = (const float*)d_in[13];
    const float* y3d   = (const float*)d_in[14];
    const float* y3e   = (const float*)d_in[15];

    const int nrows = in_sizes[0] / 2;

    const int nA = (nrows + TPB - 1) / TPB;                 // 1024
    const int nB = (nrows + ROWS_PER_B - 1) / ROWS_PER_B;   // 2048

    // ws layout (all plain-stored every call — no memset needed):
    // pA: nA*8 doubles | pB: nB doubles | mask: nrows bytes
    double*        pA   = (double*)d_ws;
    double*        pB   = (double*)((char*)d_ws + (size_t)nA * 8 * sizeof(double));
    unsigned char* mask = (unsigned char*)((char*)pB + (size_t)nB * sizeof(double));

    hml_A<<<nA, TPB, 0, stream>>>(
        l1p, l2pCC, l2pURW, l1y, l2yCC, l2yURW, nrows, pA, mask);

    hml_B<<<nB, TPB, 0, stream>>>(
        p3a, p3b, p3c, p3d, p3e, y3a, y3b, y3c, y3d, y3e,
        mask, nrows, pB);

    hml_final<<<1, TPB, 0, stream>>>(pA, nA, pB, nB, (float*)d_out, nrows);
}